// Round 6
// baseline (381.916 us; speedup 1.0000x reference)
//
#include <hip/hip_runtime.h>
#include <hip/hip_bf16.h>
#include <hip/hip_fp16.h>
#include <cstdint>
#include <cstddef>

#define BB 32
#define NN 256
#define MM 256
#define DD 512
#define NEGF (-1e9f)
#define LOG2E 1.4426950408889634f
#define WARR 131328  // 513*256 floats: one (batch, diag-array) plane

typedef __fp16 h2 __attribute__((ext_vector_type(2)));

__device__ __forceinline__ uint32_t pack_q(float a, float b) {
  h2 r = __builtin_amdgcn_cvt_pkrtz(a, b);      // (q1,q3) -> 2x fp16
  return __builtin_bit_cast(uint32_t, r);
}
__device__ __forceinline__ float2 unpack_q(uint32_t u) {
  h2 r = __builtin_bit_cast(h2, u);
  return make_float2((float)r.x, (float)r.y);
}

__device__ __forceinline__ float softplus_f(float x) {
  return fmaxf(x, 0.f) + __logf(1.f + __expf(-fabsf(x)));
}
__device__ __forceinline__ float logsig_f(float x) {
  return fminf(x, 0.f) - __logf(1.f + __expf(-fabsf(x)));
}

// ---------------- GEMM + activation + diag-layout side store ----------------
template<int OP>
__global__ __launch_bounds__(256) void gemm_act(const float* __restrict__ X,
                                                const float* __restrict__ Y,
                                                float* __restrict__ out,
                                                float* __restrict__ diag) {
  const int b  = blockIdx.z;
  const int m0 = blockIdx.y * 64;
  const int n0 = blockIdx.x * 64;
  const float* Xb = X + (size_t)b * NN * DD;
  const float* Yb = Y + (size_t)b * MM * DD;
  float* diagb = diag + (size_t)b * WARR;

  __shared__ float xs[16][68];
  __shared__ float ys[16][68];

  const int t  = threadIdx.x;
  const int tm = t >> 4;
  const int tn = t & 15;
  const int lr = t >> 2;
  const int lk = (t & 3) << 2;

  float acc[4][4];
  #pragma unroll
  for (int a = 0; a < 4; ++a)
    #pragma unroll
    for (int c = 0; c < 4; ++c) acc[a][c] = 0.f;

  for (int k0 = 0; k0 < DD; k0 += 16) {
    float4 xv = *(const float4*)(Xb + (size_t)(m0 + lr) * DD + k0 + lk);
    float4 yv = *(const float4*)(Yb + (size_t)(n0 + lr) * DD + k0 + lk);
    __syncthreads();
    xs[lk + 0][lr] = xv.x; xs[lk + 1][lr] = xv.y;
    xs[lk + 2][lr] = xv.z; xs[lk + 3][lr] = xv.w;
    ys[lk + 0][lr] = yv.x; ys[lk + 1][lr] = yv.y;
    ys[lk + 2][lr] = yv.z; ys[lk + 3][lr] = yv.w;
    __syncthreads();
    #pragma unroll
    for (int kk = 0; kk < 16; ++kk) {
      float4 xr = *(const float4*)&xs[kk][tm << 2];
      float4 yr = *(const float4*)&ys[kk][tn << 2];
      float xa[4] = {xr.x, xr.y, xr.z, xr.w};
      float ya[4] = {yr.x, yr.y, yr.z, yr.w};
      #pragma unroll
      for (int a = 0; a < 4; ++a)
        #pragma unroll
        for (int c = 0; c < 4; ++c)
          acc[a][c] = fmaf(xa[a], ya[c], acc[a][c]);
    }
  }

  #pragma unroll
  for (int a = 0; a < 4; ++a) {
    const int row = m0 + (tm << 2) + a;
    float4 o;
    float* po = (float*)&o;
    #pragma unroll
    for (int c = 0; c < 4; ++c) {
      const float v = acc[a][c];
      const float act = (OP == 0) ? softplus_f(v) : logsig_f(v);
      po[c] = act;
      const int col = n0 + (tn << 2) + c;
      diagb[(size_t)(row + col + 2) * 256 + row] = act * LOG2E;  // base-2 domain
    }
    *(float4*)(out + (size_t)b * NN * MM + (size_t)row * MM + n0 + (tn << 2)) = o;
  }
}

// ---------------- wave-synchronous soft-NW fwd+bwd, depth-8 pipeline --------
// One 64-lane wave per batch; lane t owns grid rows 4t+1..4t+4.
// CRITICAL: inner 8-step loops are #pragma unroll so all ring-buffer indices
// are compile-time constants -> pipeline state stays in VGPRs (rule #20:
// runtime-indexed arrays go to scratch, which silently kills the prefetch).
__global__ __launch_bounds__(64) void nw_wave(const float* __restrict__ thD,
                                              const float* __restrict__ aD,
                                              uint4* __restrict__ qpD,
                                              float* __restrict__ aln) {
  const int b = blockIdx.x;
  const int t = threadIdx.x;  // 0..63
  const float4* th4 = (const float4*)(thD + (size_t)b * WARR);
  const float4* a4  = (const float4*)(aD  + (size_t)b * WARR);
  uint4* qp = qpD + (size_t)b * (513 * 64);
  float* ALN = aln + (size_t)b * NN * MM;
  const int i0 = 4 * t + 1;

  // ---------- forward ----------
  float vp[4], vp2[4];
  #pragma unroll
  for (int k = 0; k < 4; ++k) { vp[k] = NEGF; vp2[k] = NEGF; }

  float4 thb[8], ab[8];
  #pragma unroll
  for (int dd = 2; dd <= 9; ++dd) {
    thb[dd & 7] = th4[dd * 64 + t];
    ab[dd & 7]  = a4[dd * 64 + t];
  }

  for (int blk = 0; blk < 64; ++blk) {
    #pragma unroll
    for (int u = 0; u < 8; ++u) {
      const int d  = 2 + blk * 8 + u;      // 2..513 (513 fully masked)
      const int sl = (2 + u) & 7;          // compile-time slot: d & 7

      float vu_in = __shfl_up(vp[3], 1);
      float vd_in = __shfl_up(vp2[3], 1);
      if (t == 0) { vu_in = NEGF; vd_in = (d == 2) ? 0.f : NEGF; }

      const float4 thc = thb[sl];
      const float4 ac  = ab[sl];
      float vnew[4];
      uint32_t pk[4];
      #pragma unroll
      for (int k = 0; k < 4; ++k) {
        const int i = i0 + k;
        const float vu = (k == 0) ? vu_in : vp[k - 1];   // V[i-1][j]
        const float vd = (k == 0) ? vd_in : vp2[k - 1];  // V[i-1][j-1]
        const float vl = vp[k];                          // V[i][j-1]
        const float a  = ((const float*)&ac)[k];
        const float th = ((const float*)&thc)[k];
        const float x0 = a + vu;
        const float x2 = a + vl;
        const float mx = fmaxf(fmaxf(x0, vd), x2);
        const float e0 = __builtin_amdgcn_exp2f(x0 - mx);
        const float e1 = __builtin_amdgcn_exp2f(vd - mx);
        const float e2 = __builtin_amdgcn_exp2f(x2 - mx);
        const float Z  = e0 + e1 + e2;
        const float rz = __builtin_amdgcn_rcpf(Z);
        const float v  = th + mx + __builtin_amdgcn_logf(Z);
        const bool valid = (i <= d - 1) && (i >= d - 256);
        vnew[k] = valid ? v : NEGF;
        pk[k] = pack_q(e0 * rz, e2 * rz);  // (q1, q3); q2 = 1-q1-q3
      }
      if (d <= 512) qp[d * 64 + t] = make_uint4(pk[0], pk[1], pk[2], pk[3]);
      #pragma unroll
      for (int k = 0; k < 4; ++k) { vp2[k] = vp[k]; vp[k] = vnew[k]; }
      if (d + 8 <= 512) {                  // refill same slot, 8 diags ahead
        thb[sl] = th4[(d + 8) * 64 + t];
        ab[sl]  = a4[(d + 8) * 64 + t];
      }
    }
  }

  // ---------- backward: E[i,j] = sum over consumers Q_c * E_c ----------
  float ep[4], ep2[4];
  #pragma unroll
  for (int k = 0; k < 4; ++k) { ep[k] = 0.f; ep2[k] = 0.f; }

  uint4 qr[8];
  #pragma unroll
  for (int x = 0; x < 8; ++x) qr[x] = make_uint4(0, 0, 0, 0);
  #pragma unroll
  for (int dd = 509; dd <= 512; ++dd) qr[dd & 7] = qp[dd * 64 + t];

  for (int blk = 0; blk < 64; ++blk) {
    #pragma unroll
    for (int u = 0; u < 8; ++u) {
      const int s   = 513 - (blk * 8 + u);  // 513..2 (513 fully masked)
      const int slA = (514 - u) & 7;        // slot of diag s+1
      const int slB = (515 - u) & 7;        // slot of diag s+2
      const int slL = (508 - u) & 7;        // slot of diag s-5 (load target)

      const float sh_e1 = __shfl_down(ep[0], 1);
      const float sh_e2 = __shfl_down(ep2[0], 1);
      const uint4 qA = qr[slA];
      const uint4 qB = qr[slB];
      const uint32_t sh_qA = (uint32_t)__shfl_down((int)qA.x, 1);
      const uint32_t sh_qB = (uint32_t)__shfl_down((int)qB.x, 1);

      float enew[4];
      #pragma unroll
      for (int k = 0; k < 4; ++k) {
        const int i = i0 + k;
        const int j = s - i;
        const bool cellv = (j >= 1) && (j <= 256);
        const uint32_t quA = (k < 3) ? (&qA.x)[k + 1] : sh_qA;  // Q(s+1), row i+1
        const uint32_t quB = (k < 3) ? (&qB.x)[k + 1] : sh_qB;  // Q(s+2), row i+1
        const uint32_t qcA = (&qA.x)[k];                        // Q(s+1), row i
        const float2 fA = unpack_q(quA);  // q1 of (i+1, j)
        const float2 fB = unpack_q(quB);  // (q1,q3) of (i+1, j+1)
        const float2 fC = unpack_q(qcA);  // q3 of (i, j+1)
        float q1u = fA.x;
        float q2d = 1.f - fB.x - fB.y;
        float q3l = fC.y;
        const float eu = (k < 3) ? ep[k + 1]  : sh_e1;
        const float ed = (k < 3) ? ep2[k + 1] : sh_e2;
        const float el = ep[k];
        q1u = (i <= 255)             ? q1u : 0.f;
        q2d = (i <= 255 && j <= 255) ? q2d : 0.f;
        q3l = (j <= 255)             ? q3l : 0.f;
        float E = q1u * eu + q2d * ed + q3l * el;
        if (s == 512 && i == 256) E = 1.f;   // terminal seed
        E = cellv ? E : 0.f;
        enew[k] = E;
        if (cellv) ALN[(size_t)(i - 1) * MM + (j - 1)] = E;
      }
      #pragma unroll
      for (int k = 0; k < 4; ++k) { ep2[k] = ep[k]; ep[k] = enew[k]; }
      if (s - 5 >= 2) qr[slL] = qp[(s - 5) * 64 + t];
    }
  }
}

// ---------------- launcher ----------------
extern "C" void kernel_launch(void* const* d_in, const int* in_sizes, int n_in,
                              void* d_out, int out_size, void* d_ws, size_t ws_size,
                              hipStream_t stream) {
  const float* zx = (const float*)d_in[0];
  const float* zy = (const float*)d_in[1];
  const float* gx = (const float*)d_in[2];
  const float* gy = (const float*)d_in[3];

  float* out   = (float*)d_out;
  float* aln   = out;                              // [B][N][M]
  float* theta = out + (size_t)BB * NN * MM;       // [B][N][M]
  float* Amat  = out + (size_t)2 * BB * NN * MM;   // [B][N][M]

  float* ws  = (float*)d_ws;
  float* thD = ws;                                 // [B][513][256] f32
  float* aD  = ws + (size_t)BB * WARR;             // [B][513][256] f32
  uint4* qpD = (uint4*)(ws + (size_t)2 * BB * WARR);  // [B][513][64] uint4 (half2 x4)

  dim3 gg(MM / 64, NN / 64, BB);
  gemm_act<0><<<gg, 256, 0, stream>>>(zx, zy, theta, thD);
  gemm_act<1><<<gg, 256, 0, stream>>>(gx, gy, Amat, aD);
  nw_wave<<<BB, 64, 0, stream>>>(thD, aD, qpD, aln);
}